// Round 3
// baseline (117.923 us; speedup 1.0000x reference)
//
#include <hip/hip_runtime.h>

#define B_  32
#define CL_ 1024
#define QL_ 512
#define D_  256
#define BM  32

typedef _Float16 f16;
typedef __attribute__((ext_vector_type(2))) _Float16 f16x2;
typedef __attribute__((ext_vector_type(4))) _Float16 f16x4;
typedef __attribute__((ext_vector_type(8))) _Float16 f16x8;
typedef __attribute__((ext_vector_type(4))) float    f32x4;

// ------- K0: q -> f16 (q_h), qT_h transpose, sqv[b,j] = q.w_q — fused ----
__global__ __launch_bounds__(256) void k0_prep(const float* __restrict__ q,
                                               const float* __restrict__ w_q,
                                               f16* __restrict__ q_h,
                                               f16* __restrict__ qT_h,
                                               float* __restrict__ sqv) {
  __shared__ f16 q_l[64][258];                 // +2 pad: row stride 516B
  int b = blockIdx.y, j0 = blockIdx.x * 64, tid = threadIdx.x;
  int r = tid >> 2, seg = tid & 3;             // row j0+r, d-quarter seg
  const float* qrow = q   + ((size_t)(b * QL_ + j0 + r)) * D_ + seg * 64;
  f16*        qhrow = q_h + ((size_t)(b * QL_ + j0 + r)) * D_ + seg * 64;
  float dot = 0.f;
  #pragma unroll
  for (int u = 0; u < 16; ++u) {
    f32x4 v  = *(const f32x4*)(qrow + 4 * u);
    f32x4 wv = *(const f32x4*)(w_q + seg * 64 + 4 * u);
    f16x4 h;
    h[0] = (f16)v[0]; h[1] = (f16)v[1]; h[2] = (f16)v[2]; h[3] = (f16)v[3];
    *(f16x4*)(&q_l[r][seg * 64 + 4 * u]) = h;
    *(f16x4*)(qhrow + 4 * u) = h;
    dot += v[0]*wv[0] + v[1]*wv[1] + v[2]*wv[2] + v[3]*wv[3];
  }
  dot += __shfl_xor(dot, 1, 64);
  dot += __shfl_xor(dot, 2, 64);
  if (seg == 0) sqv[b * QL_ + j0 + r] = dot;
  __syncthreads();
  f16* qTb = qT_h + (size_t)b * D_ * QL_ + j0;
  #pragma unroll
  for (int s = 0; s < 32; ++s) {
    int e = tid + 256 * s;                     // 256 d x 32 j-pairs
    int d = e >> 5, j2 = (e & 31) * 2;
    f16x2 p;
    p[0] = q_l[j2][d];
    p[1] = q_l[j2 + 1][d];
    *(f16x2*)(qTb + (size_t)d * QL_ + j2) = p;
  }
}

// ---------------- K1: scores + softmax + PV + epilogue -------------------
// 512 thr = 8 waves. B-operand fragments direct from global (L2/L3).
// All `out` stores NON-TEMPORAL: the 402MB store stream must not sweep L3
// (c/q_h/qT_h working set ~208MB fits 256MB L3 across replays).
__global__ __launch_bounds__(512, 4) void k1_attn(
    const float* __restrict__ c, const f16* __restrict__ q_h,
    const f16* __restrict__ qT_h, const float* __restrict__ sqv,
    const float* __restrict__ w_c, const float* __restrict__ w_cq,
    float* __restrict__ out, float* __restrict__ mrow)
{
  __shared__ alignas(16) char smem[38784];
  f16 (*cw_t)[264] = (f16 (*)[264])(smem);
  f16 (*P_t)[520]  = (f16 (*)[520])(smem);
  float* sqv_l = (float*)(smem + 33280);
  float* wcq_l = (float*)(smem + 35328);
  float* wc_l  = (float*)(smem + 36352);
  float* scv_l = (float*)(smem + 37376);
  float (*red)[BM] = (float (*)[BM])(smem + 37504);
  float* mf = (float*)(smem + 38528);
  float* lf = (float*)(smem + 38656);

  const int tid = threadIdx.x;
  const int w = tid >> 6, l = tid & 63, g = l >> 4, l15 = l & 15;
  const int lin = blockIdx.x, xcd = lin & 7, slot = lin >> 3;
  const int b = (xcd << 2) | (slot >> 5);
  const int i0 = (slot & 31) * BM;

  if (tid < 256) { wcq_l[tid] = w_cq[tid]; wc_l[tid] = w_c[tid]; }
  sqv_l[tid] = sqv[b * QL_ + tid];
  __syncthreads();

  // stage cw_t = f16(c * w_cq); scv = c . w_c (f32)
  {
    int r = tid >> 4, seg = tid & 15;
    const float* crow = c + (size_t)(b * CL_ + i0 + r) * D_;
    float dot = 0.f;
    #pragma unroll
    for (int u = 0; u < 4; ++u) {
      int d = seg * 16 + u * 4;
      f32x4 v  = *(const f32x4*)(crow + d);
      f32x4 wv = *(const f32x4*)(wcq_l + d);
      f32x4 w2 = *(const f32x4*)(wc_l + d);
      f16x4 h;
      h[0] = (f16)(v[0]*wv[0]); h[1] = (f16)(v[1]*wv[1]);
      h[2] = (f16)(v[2]*wv[2]); h[3] = (f16)(v[3]*wv[3]);
      *(f16x4*)(&cw_t[r][d]) = h;
      dot += v[0]*w2[0] + v[1]*w2[1] + v[2]*w2[2] + v[3]*w2[3];
    }
    dot += __shfl_xor(dot, 1, 64); dot += __shfl_xor(dot, 2, 64);
    dot += __shfl_xor(dot, 4, 64); dot += __shfl_xor(dot, 8, 64);
    if (seg == 0) scv_l[r] = dot;
  }
  __syncthreads();

  // ---- Phase A: U = (c*w_cq) @ q^T; wave w owns j in [64w,64w+64) ------
  f32x4 acc[2][4];
  #pragma unroll
  for (int fi = 0; fi < 2; ++fi)
    #pragma unroll
    for (int fj = 0; fj < 4; ++fj)
      acc[fi][fj] = (f32x4){0.f,0.f,0.f,0.f};

  const f16* qhb = q_h + (size_t)b * QL_ * D_;
  #pragma unroll
  for (int dk = 0; dk < 8; ++dk) {
    f16x8 a0 = *(const f16x8*)(&cw_t[l15     ][dk * 32 + 8 * g]);
    f16x8 a1 = *(const f16x8*)(&cw_t[16 + l15][dk * 32 + 8 * g]);
    #pragma unroll
    for (int fj = 0; fj < 4; ++fj) {
      f16x8 bf = *(const f16x8*)(qhb + (size_t)(64*w + 16*fj + l15) * D_ + dk * 32 + 8 * g);
      acc[0][fj] = __builtin_amdgcn_mfma_f32_16x16x32_f16(a0, bf, acc[0][fj], 0, 0, 0);
      acc[1][fj] = __builtin_amdgcn_mfma_f32_16x16x32_f16(a1, bf, acc[1][fj], 0, 0, 0);
    }
  }

  // ---- Phase B: softmax over j ----
  float rmax[2][4];
  #pragma unroll
  for (int fi = 0; fi < 2; ++fi) {
    #pragma unroll
    for (int r = 0; r < 4; ++r) {
      float mx = -1e30f;
      #pragma unroll
      for (int fj = 0; fj < 4; ++fj) {
        float v = acc[fi][fj][r] + sqv_l[w * 64 + 16 * fj + l15];
        acc[fi][fj][r] = v;
        mx = fmaxf(mx, v);
      }
      mx = fmaxf(mx, __shfl_xor(mx, 1, 64));
      mx = fmaxf(mx, __shfl_xor(mx, 2, 64));
      mx = fmaxf(mx, __shfl_xor(mx, 4, 64));
      mx = fmaxf(mx, __shfl_xor(mx, 8, 64));
      rmax[fi][r] = mx;
    }
  }
  if (l15 == 0) {
    #pragma unroll
    for (int fi = 0; fi < 2; ++fi)
      #pragma unroll
      for (int r = 0; r < 4; ++r)
        red[w][16 * fi + 4 * g + r] = rmax[fi][r];
  }
  __syncthreads();
  if (tid < BM) {
    float m = red[0][tid];
    #pragma unroll
    for (int w2 = 1; w2 < 8; ++w2) m = fmaxf(m, red[w2][tid]);
    mf[tid] = m;
    mrow[b * CL_ + i0 + tid] = m + scv_l[tid];
  }
  __syncthreads();

  float rsum[2][4];
  #pragma unroll
  for (int fi = 0; fi < 2; ++fi) {
    #pragma unroll
    for (int r = 0; r < 4; ++r) {
      int il = 16 * fi + 4 * g + r;
      float mv = mf[il];
      float s = 0.f;
      #pragma unroll
      for (int fj = 0; fj < 4; ++fj) {
        float p = __expf(acc[fi][fj][r] - mv);
        s += p;
        P_t[il][w * 64 + 16 * fj + l15] = (f16)p;
      }
      s += __shfl_xor(s, 1, 64); s += __shfl_xor(s, 2, 64);
      s += __shfl_xor(s, 4, 64); s += __shfl_xor(s, 8, 64);
      rsum[fi][r] = s;
    }
  }
  if (l15 == 0) {
    #pragma unroll
    for (int fi = 0; fi < 2; ++fi)
      #pragma unroll
      for (int r = 0; r < 4; ++r)
        red[w][16 * fi + 4 * g + r] = rsum[fi][r];
  }
  __syncthreads();
  if (tid < BM) {
    float s = 0.f;
    #pragma unroll
    for (int w2 = 0; w2 < 8; ++w2) s += red[w2][tid];
    lf[tid] = 1.0f / s;
  }
  __syncthreads();

  // ---- Phase C: O = P @ q; wave w owns d in [32w,32w+32) ---------------
  f32x4 o[2][2];
  o[0][0] = (f32x4){0.f,0.f,0.f,0.f}; o[0][1] = o[0][0];
  o[1][0] = o[0][0];                  o[1][1] = o[0][0];
  const f16* qTb = qT_h + (size_t)b * D_ * QL_;
  #pragma unroll
  for (int jt = 0; jt < 16; ++jt) {
    f16x8 p0 = *(const f16x8*)(&P_t[l15     ][jt * 32 + 8 * g]);
    f16x8 p1 = *(const f16x8*)(&P_t[16 + l15][jt * 32 + 8 * g]);
    #pragma unroll
    for (int fd = 0; fd < 2; ++fd) {
      f16x8 qf = *(const f16x8*)(qTb + (size_t)(32*w + 16*fd + l15) * QL_ + jt * 32 + 8 * g);
      o[0][fd] = __builtin_amdgcn_mfma_f32_16x16x32_f16(p0, qf, o[0][fd], 0, 0, 0);
      o[1][fd] = __builtin_amdgcn_mfma_f32_16x16x32_f16(p1, qf, o[1][fd], 0, 0, 0);
    }
  }

  // ---- Epilogue: non-temporal stores (don't sweep L3) ------------------
  #pragma unroll
  for (int fi = 0; fi < 2; ++fi) {
    #pragma unroll
    for (int fd = 0; fd < 2; ++fd) {
      #pragma unroll
      for (int r = 0; r < 4; ++r) {
        int il = 16 * fi + 4 * g + r;
        int d  = w * 32 + 16 * fd + l15;
        size_t rowoff = (size_t)(b * CL_ + i0 + il);
        float c2q = o[fi][fd][r] * lf[il];
        float cv  = c[rowoff * D_ + d];
        float* ob = out + rowoff * (4 * D_);
        __builtin_nontemporal_store(cv,        ob + d);
        __builtin_nontemporal_store(c2q,       ob + D_ + d);
        __builtin_nontemporal_store(cv * c2q,  ob + 2 * D_ + d);
      }
    }
  }
}

// ------- K2a: bvec[b,:] = softmax_i(mrow[b,:]) (normalized, f32) ---------
__global__ __launch_bounds__(256) void k2a_bvec(const float* __restrict__ mrow,
                                                float* __restrict__ bvec) {
  __shared__ float red[256];
  int b = blockIdx.x, tid = threadIdx.x;
  f32x4 v = *(const f32x4*)(mrow + b * CL_ + tid * 4);
  float mx = fmaxf(fmaxf(v[0], v[1]), fmaxf(v[2], v[3]));
  red[tid] = mx;
  __syncthreads();
  for (int s = 128; s > 0; s >>= 1) {
    if (tid < s) red[tid] = fmaxf(red[tid], red[tid + s]);
    __syncthreads();
  }
  float gmx = red[0];
  __syncthreads();
  f32x4 e;
  e[0] = __expf(v[0] - gmx); e[1] = __expf(v[1] - gmx);
  e[2] = __expf(v[2] - gmx); e[3] = __expf(v[3] - gmx);
  red[tid] = e[0] + e[1] + e[2] + e[3];
  __syncthreads();
  for (int s = 128; s > 0; s >>= 1) {
    if (tid < s) red[tid] += red[tid + s];
    __syncthreads();
  }
  float inv = 1.0f / red[0];
  e[0] *= inv; e[1] *= inv; e[2] *= inv; e[3] *= inv;
  *(f32x4*)(bvec + b * CL_ + tid * 4) = e;
}

// ------- K2b: part[b,ch,:] = sum_{i in chunk} bvec[i] * c[i,:] -----------
__global__ __launch_bounds__(256) void k2b_part(const float* __restrict__ c,
                                                const float* __restrict__ bvec,
                                                float* __restrict__ part) {
  __shared__ f32x4 pl[4][64];
  int ch = blockIdx.x, b = blockIdx.y, tid = threadIdx.x;
  int ro = tid >> 6, dl = tid & 63;
  const float* cb = c + ((size_t)b * CL_ + ch * 128) * D_;
  const float* bv = bvec + b * CL_ + ch * 128;
  f32x4 acc = (f32x4){0.f, 0.f, 0.f, 0.f};
  for (int i = ro; i < 128; i += 4) {
    float wgt = bv[i];
    f32x4 v = *(const f32x4*)(cb + (size_t)i * D_ + dl * 4);
    acc[0] += wgt * v[0]; acc[1] += wgt * v[1];
    acc[2] += wgt * v[2]; acc[3] += wgt * v[3];
  }
  pl[ro][dl] = acc;
  __syncthreads();
  if (tid < 64) {
    f32x4 s = (pl[0][tid] + pl[1][tid]) + (pl[2][tid] + pl[3][tid]);
    *(f32x4*)(part + ((size_t)(b * 8 + ch)) * D_ + tid * 4) = s;
  }
}

// ------- K2c: q2c[b,:] = sum_ch part[b,ch,:] -----------------------------
__global__ __launch_bounds__(256) void k2c_red(const float* __restrict__ part,
                                               float* __restrict__ q2c) {
  int b = blockIdx.x, d = threadIdx.x;
  float s = 0.f;
  #pragma unroll
  for (int ch = 0; ch < 8; ++ch) s += part[((size_t)(b * 8 + ch)) * D_ + d];
  q2c[b * D_ + d] = s;
}

// ------- K3: out[3D:4D] = c * q2c (broadcast), non-temporal stores -------
__global__ __launch_bounds__(256) void k3_tail(const float* __restrict__ c,
                                               const float* __restrict__ q2c,
                                               float* __restrict__ out) {
  size_t idx = (size_t)blockIdx.x * 256 + threadIdx.x;   // B*CL*64 float4s
  int b   = (int)(idx >> 16);
  int rem = (int)(idx & 65535);
  int i = rem >> 6, d4 = (rem & 63) * 4;
  f32x4 cv = *(const f32x4*)(c + (size_t)(b * CL_ + i) * D_ + d4);
  f32x4 gv = *(const f32x4*)(q2c + b * D_ + d4);
  f32x4 r;
  r[0] = cv[0]*gv[0]; r[1] = cv[1]*gv[1]; r[2] = cv[2]*gv[2]; r[3] = cv[3]*gv[3];
  __builtin_nontemporal_store(r, (f32x4*)(out + (size_t)(b * CL_ + i) * (4 * D_) + 3 * D_ + d4));
}

extern "C" void kernel_launch(void* const* d_in, const int* in_sizes, int n_in,
                              void* d_out, int out_size, void* d_ws, size_t ws_size,
                              hipStream_t stream) {
  const float* c    = (const float*)d_in[0];
  const float* q    = (const float*)d_in[1];
  const float* w_c  = (const float*)d_in[2];
  const float* w_q  = (const float*)d_in[4];
  const float* w_cq = (const float*)d_in[6];
  float* out = (float*)d_out;
  char* ws = (char*)d_ws;
  f16*   q_h  = (f16*)ws;                       //  8,388,608 B
  f16*   qT_h = (f16*)(ws + 8388608);           //  8,388,608 B
  float* sqv  = (float*)(ws + 16777216);        //     65,536 B
  float* mrow = (float*)(ws + 16842752);        //    131,072 B
  float* bvec = (float*)(ws + 16973824);        //    131,072 B
  float* part = (float*)(ws + 17104896);        //    262,144 B
  float* q2c  = (float*)(ws + 17367040);        //     32,768 B (tot 17,399,808)

  hipLaunchKernelGGL(k0_prep,  dim3(8, 32),  dim3(256), 0, stream, q, w_q, q_h, qT_h, sqv);
  hipLaunchKernelGGL(k1_attn,  dim3(1024),   dim3(512), 0, stream,
                     c, q_h, qT_h, sqv, w_c, w_cq, out, mrow);
  hipLaunchKernelGGL(k2a_bvec, dim3(32),     dim3(256), 0, stream, mrow, bvec);
  hipLaunchKernelGGL(k2b_part, dim3(8, 32),  dim3(256), 0, stream, c, bvec, part);
  hipLaunchKernelGGL(k2c_red,  dim3(32),     dim3(256), 0, stream, part, q2c);
  hipLaunchKernelGGL(k3_tail,  dim3(8192),   dim3(256), 0, stream, c, q2c, out);
}

// Round 4
// 115.843 us; speedup vs baseline: 1.0180x; 1.0180x over previous
//
#include <hip/hip_runtime.h>

#define B_  32
#define CL_ 1024
#define QL_ 512
#define D_  256
#define BM  32

typedef _Float16 f16;
typedef __attribute__((ext_vector_type(2))) _Float16 f16x2;
typedef __attribute__((ext_vector_type(4))) _Float16 f16x4;
typedef __attribute__((ext_vector_type(8))) _Float16 f16x8;
typedef __attribute__((ext_vector_type(4))) float    f32x4;

// ------- K0: q -> f16 (q_h), qT_h transpose, sqv[b,j] = q.w_q — fused ----
__global__ __launch_bounds__(256) void k0_prep(const float* __restrict__ q,
                                               const float* __restrict__ w_q,
                                               f16* __restrict__ q_h,
                                               f16* __restrict__ qT_h,
                                               float* __restrict__ sqv) {
  __shared__ f16 q_l[64][258];                 // +2 pad: row stride 516B
  int b = blockIdx.y, j0 = blockIdx.x * 64, tid = threadIdx.x;
  int r = tid >> 2, seg = tid & 3;             // row j0+r, d-quarter seg
  const float* qrow = q   + ((size_t)(b * QL_ + j0 + r)) * D_ + seg * 64;
  f16*        qhrow = q_h + ((size_t)(b * QL_ + j0 + r)) * D_ + seg * 64;
  float dot = 0.f;
  #pragma unroll
  for (int u = 0; u < 16; ++u) {
    f32x4 v  = *(const f32x4*)(qrow + 4 * u);
    f32x4 wv = *(const f32x4*)(w_q + seg * 64 + 4 * u);
    f16x4 h;
    h[0] = (f16)v[0]; h[1] = (f16)v[1]; h[2] = (f16)v[2]; h[3] = (f16)v[3];
    *(f16x4*)(&q_l[r][seg * 64 + 4 * u]) = h;
    *(f16x4*)(qhrow + 4 * u) = h;
    dot += v[0]*wv[0] + v[1]*wv[1] + v[2]*wv[2] + v[3]*wv[3];
  }
  dot += __shfl_xor(dot, 1, 64);
  dot += __shfl_xor(dot, 2, 64);
  if (seg == 0) sqv[b * QL_ + j0 + r] = dot;
  __syncthreads();
  f16* qTb = qT_h + (size_t)b * D_ * QL_ + j0;
  #pragma unroll
  for (int s = 0; s < 32; ++s) {
    int e = tid + 256 * s;                     // 256 d x 32 j-pairs
    int d = e >> 5, j2 = (e & 31) * 2;
    f16x2 p;
    p[0] = q_l[j2][d];
    p[1] = q_l[j2 + 1][d];
    *(f16x2*)(qTb + (size_t)d * QL_ + j2) = p;
  }
}

// ---------------- K1: scores + softmax + PV + epilogue -------------------
// 512 thr = 8 waves. B-operand fragments direct from global (L2-resident),
// with DEPTH-2 REGISTER PREFETCH to hide ~200cy L2 latency under MFMAs.
__global__ __launch_bounds__(512, 4) void k1_attn(
    const float* __restrict__ c, const f16* __restrict__ q_h,
    const f16* __restrict__ qT_h, const float* __restrict__ sqv,
    const float* __restrict__ w_c, const float* __restrict__ w_cq,
    float* __restrict__ out, float* __restrict__ mrow)
{
  __shared__ alignas(16) char smem[38784];
  f16 (*cw_t)[264] = (f16 (*)[264])(smem);
  f16 (*P_t)[520]  = (f16 (*)[520])(smem);
  float* sqv_l = (float*)(smem + 33280);
  float* wcq_l = (float*)(smem + 35328);
  float* wc_l  = (float*)(smem + 36352);
  float* scv_l = (float*)(smem + 37376);
  float (*red)[BM] = (float (*)[BM])(smem + 37504);
  float* mf = (float*)(smem + 38528);
  float* lf = (float*)(smem + 38656);

  const int tid = threadIdx.x;
  const int w = tid >> 6, l = tid & 63, g = l >> 4, l15 = l & 15;
  const int lin = blockIdx.x, xcd = lin & 7, slot = lin >> 3;
  const int b = (xcd << 2) | (slot >> 5);
  const int i0 = (slot & 31) * BM;

  if (tid < 256) { wcq_l[tid] = w_cq[tid]; wc_l[tid] = w_c[tid]; }
  sqv_l[tid] = sqv[b * QL_ + tid];
  __syncthreads();

  // stage cw_t = f16(c * w_cq); scv = c . w_c (f32)
  {
    int r = tid >> 4, seg = tid & 15;
    const float* crow = c + (size_t)(b * CL_ + i0 + r) * D_;
    float dot = 0.f;
    #pragma unroll
    for (int u = 0; u < 4; ++u) {
      int d = seg * 16 + u * 4;
      f32x4 v  = *(const f32x4*)(crow + d);
      f32x4 wv = *(const f32x4*)(wcq_l + d);
      f32x4 w2 = *(const f32x4*)(wc_l + d);
      f16x4 h;
      h[0] = (f16)(v[0]*wv[0]); h[1] = (f16)(v[1]*wv[1]);
      h[2] = (f16)(v[2]*wv[2]); h[3] = (f16)(v[3]*wv[3]);
      *(f16x4*)(&cw_t[r][d]) = h;
      dot += v[0]*w2[0] + v[1]*w2[1] + v[2]*w2[2] + v[3]*w2[3];
    }
    dot += __shfl_xor(dot, 1, 64); dot += __shfl_xor(dot, 2, 64);
    dot += __shfl_xor(dot, 4, 64); dot += __shfl_xor(dot, 8, 64);
    if (seg == 0) scv_l[r] = dot;
  }
  __syncthreads();

  // ---- Phase A: U = (c*w_cq) @ q^T; wave w owns j in [64w,64w+64) ------
  // B fragments prefetched one dk-iteration ahead (software pipeline).
  f32x4 acc[2][4];
  #pragma unroll
  for (int fi = 0; fi < 2; ++fi)
    #pragma unroll
    for (int fj = 0; fj < 4; ++fj)
      acc[fi][fj] = (f32x4){0.f,0.f,0.f,0.f};

  const f16* qhb = q_h + (size_t)b * QL_ * D_;
  const f16* qr0 = qhb + (size_t)(64*w + l15     ) * D_ + 8 * g;
  const f16* qr1 = qhb + (size_t)(64*w + 16 + l15) * D_ + 8 * g;
  const f16* qr2 = qhb + (size_t)(64*w + 32 + l15) * D_ + 8 * g;
  const f16* qr3 = qhb + (size_t)(64*w + 48 + l15) * D_ + 8 * g;
  f16x8 bf0 = *(const f16x8*)(qr0);
  f16x8 bf1 = *(const f16x8*)(qr1);
  f16x8 bf2 = *(const f16x8*)(qr2);
  f16x8 bf3 = *(const f16x8*)(qr3);
  #pragma unroll
  for (int dk = 0; dk < 8; ++dk) {
    f16x8 a0 = *(const f16x8*)(&cw_t[l15     ][dk * 32 + 8 * g]);
    f16x8 a1 = *(const f16x8*)(&cw_t[16 + l15][dk * 32 + 8 * g]);
    f16x8 nf0, nf1, nf2, nf3;
    if (dk < 7) {
      nf0 = *(const f16x8*)(qr0 + (dk + 1) * 32);
      nf1 = *(const f16x8*)(qr1 + (dk + 1) * 32);
      nf2 = *(const f16x8*)(qr2 + (dk + 1) * 32);
      nf3 = *(const f16x8*)(qr3 + (dk + 1) * 32);
    }
    acc[0][0] = __builtin_amdgcn_mfma_f32_16x16x32_f16(a0, bf0, acc[0][0], 0, 0, 0);
    acc[1][0] = __builtin_amdgcn_mfma_f32_16x16x32_f16(a1, bf0, acc[1][0], 0, 0, 0);
    acc[0][1] = __builtin_amdgcn_mfma_f32_16x16x32_f16(a0, bf1, acc[0][1], 0, 0, 0);
    acc[1][1] = __builtin_amdgcn_mfma_f32_16x16x32_f16(a1, bf1, acc[1][1], 0, 0, 0);
    acc[0][2] = __builtin_amdgcn_mfma_f32_16x16x32_f16(a0, bf2, acc[0][2], 0, 0, 0);
    acc[1][2] = __builtin_amdgcn_mfma_f32_16x16x32_f16(a1, bf2, acc[1][2], 0, 0, 0);
    acc[0][3] = __builtin_amdgcn_mfma_f32_16x16x32_f16(a0, bf3, acc[0][3], 0, 0, 0);
    acc[1][3] = __builtin_amdgcn_mfma_f32_16x16x32_f16(a1, bf3, acc[1][3], 0, 0, 0);
    bf0 = nf0; bf1 = nf1; bf2 = nf2; bf3 = nf3;
  }

  // ---- Phase B: softmax over j ----
  float rmax[2][4];
  #pragma unroll
  for (int fi = 0; fi < 2; ++fi) {
    #pragma unroll
    for (int r = 0; r < 4; ++r) {
      float mx = -1e30f;
      #pragma unroll
      for (int fj = 0; fj < 4; ++fj) {
        float v = acc[fi][fj][r] + sqv_l[w * 64 + 16 * fj + l15];
        acc[fi][fj][r] = v;
        mx = fmaxf(mx, v);
      }
      mx = fmaxf(mx, __shfl_xor(mx, 1, 64));
      mx = fmaxf(mx, __shfl_xor(mx, 2, 64));
      mx = fmaxf(mx, __shfl_xor(mx, 4, 64));
      mx = fmaxf(mx, __shfl_xor(mx, 8, 64));
      rmax[fi][r] = mx;
    }
  }
  if (l15 == 0) {
    #pragma unroll
    for (int fi = 0; fi < 2; ++fi)
      #pragma unroll
      for (int r = 0; r < 4; ++r)
        red[w][16 * fi + 4 * g + r] = rmax[fi][r];
  }
  __syncthreads();
  if (tid < BM) {
    float m = red[0][tid];
    #pragma unroll
    for (int w2 = 1; w2 < 8; ++w2) m = fmaxf(m, red[w2][tid]);
    mf[tid] = m;
    mrow[b * CL_ + i0 + tid] = m + scv_l[tid];
  }
  __syncthreads();

  float rsum[2][4];
  #pragma unroll
  for (int fi = 0; fi < 2; ++fi) {
    #pragma unroll
    for (int r = 0; r < 4; ++r) {
      int il = 16 * fi + 4 * g + r;
      float mv = mf[il];
      float s = 0.f;
      #pragma unroll
      for (int fj = 0; fj < 4; ++fj) {
        float p = __expf(acc[fi][fj][r] - mv);
        s += p;
        P_t[il][w * 64 + 16 * fj + l15] = (f16)p;
      }
      s += __shfl_xor(s, 1, 64); s += __shfl_xor(s, 2, 64);
      s += __shfl_xor(s, 4, 64); s += __shfl_xor(s, 8, 64);
      rsum[fi][r] = s;
    }
  }
  if (l15 == 0) {
    #pragma unroll
    for (int fi = 0; fi < 2; ++fi)
      #pragma unroll
      for (int r = 0; r < 4; ++r)
        red[w][16 * fi + 4 * g + r] = rsum[fi][r];
  }
  __syncthreads();
  if (tid < BM) {
    float s = 0.f;
    #pragma unroll
    for (int w2 = 0; w2 < 8; ++w2) s += red[w2][tid];
    lf[tid] = 1.0f / s;
  }
  __syncthreads();

  // ---- Phase C: O = P @ q; wave w owns d in [32w,32w+32); prefetched ---
  f32x4 o[2][2];
  o[0][0] = (f32x4){0.f,0.f,0.f,0.f}; o[0][1] = o[0][0];
  o[1][0] = o[0][0];                  o[1][1] = o[0][0];
  const f16* qTb = qT_h + (size_t)b * D_ * QL_;
  const f16* tr0 = qTb + (size_t)(32*w + l15     ) * QL_ + 8 * g;
  const f16* tr1 = qTb + (size_t)(32*w + 16 + l15) * QL_ + 8 * g;
  f16x8 qf0 = *(const f16x8*)(tr0);
  f16x8 qf1 = *(const f16x8*)(tr1);
  #pragma unroll
  for (int jt = 0; jt < 16; ++jt) {
    f16x8 p0 = *(const f16x8*)(&P_t[l15     ][jt * 32 + 8 * g]);
    f16x8 p1 = *(const f16x8*)(&P_t[16 + l15][jt * 32 + 8 * g]);
    f16x8 nq0, nq1;
    if (jt < 15) {
      nq0 = *(const f16x8*)(tr0 + (jt + 1) * 32);
      nq1 = *(const f16x8*)(tr1 + (jt + 1) * 32);
    }
    o[0][0] = __builtin_amdgcn_mfma_f32_16x16x32_f16(p0, qf0, o[0][0], 0, 0, 0);
    o[1][0] = __builtin_amdgcn_mfma_f32_16x16x32_f16(p1, qf0, o[1][0], 0, 0, 0);
    o[0][1] = __builtin_amdgcn_mfma_f32_16x16x32_f16(p0, qf1, o[0][1], 0, 0, 0);
    o[1][1] = __builtin_amdgcn_mfma_f32_16x16x32_f16(p1, qf1, o[1][1], 0, 0, 0);
    qf0 = nq0; qf1 = nq1;
  }

  // ---- Epilogue: out[0:D]=c, [D:2D]=c2q, [2D:3D]=c*c2q ----
  #pragma unroll
  for (int fi = 0; fi < 2; ++fi) {
    #pragma unroll
    for (int fd = 0; fd < 2; ++fd) {
      #pragma unroll
      for (int r = 0; r < 4; ++r) {
        int il = 16 * fi + 4 * g + r;
        int d  = w * 32 + 16 * fd + l15;
        size_t rowoff = (size_t)(b * CL_ + i0 + il);
        float c2q = o[fi][fd][r] * lf[il];
        float cv  = c[rowoff * D_ + d];
        float* ob = out + rowoff * (4 * D_);
        ob[d]          = cv;
        ob[D_ + d]     = c2q;
        ob[2 * D_ + d] = cv * c2q;
      }
    }
  }
}

// ------- K2a: bvec[b,:] = softmax_i(mrow[b,:]) (normalized, f32) ---------
__global__ __launch_bounds__(256) void k2a_bvec(const float* __restrict__ mrow,
                                                float* __restrict__ bvec) {
  __shared__ float red[256];
  int b = blockIdx.x, tid = threadIdx.x;
  f32x4 v = *(const f32x4*)(mrow + b * CL_ + tid * 4);
  float mx = fmaxf(fmaxf(v[0], v[1]), fmaxf(v[2], v[3]));
  red[tid] = mx;
  __syncthreads();
  for (int s = 128; s > 0; s >>= 1) {
    if (tid < s) red[tid] = fmaxf(red[tid], red[tid + s]);
    __syncthreads();
  }
  float gmx = red[0];
  __syncthreads();
  f32x4 e;
  e[0] = __expf(v[0] - gmx); e[1] = __expf(v[1] - gmx);
  e[2] = __expf(v[2] - gmx); e[3] = __expf(v[3] - gmx);
  red[tid] = e[0] + e[1] + e[2] + e[3];
  __syncthreads();
  for (int s = 128; s > 0; s >>= 1) {
    if (tid < s) red[tid] += red[tid + s];
    __syncthreads();
  }
  float inv = 1.0f / red[0];
  e[0] *= inv; e[1] *= inv; e[2] *= inv; e[3] *= inv;
  *(f32x4*)(bvec + b * CL_ + tid * 4) = e;
}

// ------- K2b: part[b,ch,:] = sum_{i in chunk} bvec[i] * c[i,:] -----------
__global__ __launch_bounds__(256) void k2b_part(const float* __restrict__ c,
                                                const float* __restrict__ bvec,
                                                float* __restrict__ part) {
  __shared__ f32x4 pl[4][64];
  int ch = blockIdx.x, b = blockIdx.y, tid = threadIdx.x;
  int ro = tid >> 6, dl = tid & 63;
  const float* cb = c + ((size_t)b * CL_ + ch * 128) * D_;
  const float* bv = bvec + b * CL_ + ch * 128;
  f32x4 acc = (f32x4){0.f, 0.f, 0.f, 0.f};
  for (int i = ro; i < 128; i += 4) {
    float wgt = bv[i];
    f32x4 v = *(const f32x4*)(cb + (size_t)i * D_ + dl * 4);
    acc[0] += wgt * v[0]; acc[1] += wgt * v[1];
    acc[2] += wgt * v[2]; acc[3] += wgt * v[3];
  }
  pl[ro][dl] = acc;
  __syncthreads();
  if (tid < 64) {
    f32x4 s = (pl[0][tid] + pl[1][tid]) + (pl[2][tid] + pl[3][tid]);
    *(f32x4*)(part + ((size_t)(b * 8 + ch)) * D_ + tid * 4) = s;
  }
}

// ------- K2c: q2c[b,:] = sum_ch part[b,ch,:] -----------------------------
__global__ __launch_bounds__(256) void k2c_red(const float* __restrict__ part,
                                               float* __restrict__ q2c) {
  int b = blockIdx.x, d = threadIdx.x;
  float s = 0.f;
  #pragma unroll
  for (int ch = 0; ch < 8; ++ch) s += part[((size_t)(b * 8 + ch)) * D_ + d];
  q2c[b * D_ + d] = s;
}

// ------- K3: out[3D:4D] = c * q2c (broadcast) ----------------------------
__global__ __launch_bounds__(256) void k3_tail(const float* __restrict__ c,
                                               const float* __restrict__ q2c,
                                               float* __restrict__ out) {
  size_t idx = (size_t)blockIdx.x * 256 + threadIdx.x;   // B*CL*64 float4s
  int b   = (int)(idx >> 16);
  int rem = (int)(idx & 65535);
  int i = rem >> 6, d4 = (rem & 63) * 4;
  f32x4 cv = *(const f32x4*)(c + (size_t)(b * CL_ + i) * D_ + d4);
  f32x4 gv = *(const f32x4*)(q2c + b * D_ + d4);
  f32x4 r;
  r[0] = cv[0]*gv[0]; r[1] = cv[1]*gv[1]; r[2] = cv[2]*gv[2]; r[3] = cv[3]*gv[3];
  *(f32x4*)(out + (size_t)(b * CL_ + i) * (4 * D_) + 3 * D_ + d4) = r;
}

extern "C" void kernel_launch(void* const* d_in, const int* in_sizes, int n_in,
                              void* d_out, int out_size, void* d_ws, size_t ws_size,
                              hipStream_t stream) {
  const float* c    = (const float*)d_in[0];
  const float* q    = (const float*)d_in[1];
  const float* w_c  = (const float*)d_in[2];
  const float* w_q  = (const float*)d_in[4];
  const float* w_cq = (const float*)d_in[6];
  float* out = (float*)d_out;
  char* ws = (char*)d_ws;
  f16*   q_h  = (f16*)ws;                       //  8,388,608 B
  f16*   qT_h = (f16*)(ws + 8388608);           //  8,388,608 B
  float* sqv  = (float*)(ws + 16777216);        //     65,536 B
  float* mrow = (float*)(ws + 16842752);        //    131,072 B
  float* bvec = (float*)(ws + 16973824);        //    131,072 B
  float* part = (float*)(ws + 17104896);        //    262,144 B
  float* q2c  = (float*)(ws + 17367040);        //     32,768 B (tot 17,399,808)

  hipLaunchKernelGGL(k0_prep,  dim3(8, 32),  dim3(256), 0, stream, q, w_q, q_h, qT_h, sqv);
  hipLaunchKernelGGL(k1_attn,  dim3(1024),   dim3(512), 0, stream,
                     c, q_h, qT_h, sqv, w_c, w_cq, out, mrow);
  hipLaunchKernelGGL(k2a_bvec, dim3(32),     dim3(256), 0, stream, mrow, bvec);
  hipLaunchKernelGGL(k2b_part, dim3(8, 32),  dim3(256), 0, stream, c, bvec, part);
  hipLaunchKernelGGL(k2c_red,  dim3(32),     dim3(256), 0, stream, part, q2c);
  hipLaunchKernelGGL(k3_tail,  dim3(8192),   dim3(256), 0, stream, c, q2c, out);
}